// Round 2
// baseline (7829.268 us; speedup 1.0000x reference)
//
#include <hip/hip_runtime.h>
#include <hip/hip_bf16.h>

// Problem constants
#define B_    32
#define S_    512
#define E_    512
#define H_    1024          // U_DIM
#define G4_   4096          // 4*U_DIM
#define NB_   128           // persistent scan blocks
#define NCOL_ 32            // n'-cols per scan block (8 j * 4 gates)

typedef __attribute__((ext_vector_type(8))) short short8;
typedef __attribute__((ext_vector_type(4))) float f32x4;

__device__ __forceinline__ float bf2f(ushort u) {
    union { unsigned u32; float f; } cv; cv.u32 = ((unsigned)u) << 16; return cv.f;
}
__device__ __forceinline__ ushort f2bf(float f) {
    union { float f; unsigned u; } cv; cv.f = f;
    unsigned u = cv.u;
    u += 0x7FFFu + ((u >> 16) & 1u);   // RNE
    return (ushort)(u >> 16);
}
__device__ __forceinline__ float tanh_fast(float x) {
    // tanh(x) = 1 - 2/(exp(2x)+1); exp(2x) = exp2(x * 2*log2(e))
    float e = __builtin_amdgcn_exp2f(x * 2.885390081777927f);
    return 1.0f - 2.0f * __builtin_amdgcn_rcpf(e + 1.0f);
}
__device__ __forceinline__ float sel4(int s, float a0, float a1, float a2, float a3) {
    return (s & 2) ? ((s & 1) ? a3 : a2) : ((s & 1) ? a1 : a0);
}

// ---------------- init: zero h0 and barrier ----------------
__global__ void init_kernel(ushort* hA, unsigned* bar) {
    int i = blockIdx.x * 256 + threadIdx.x;
    if (i == 0) *bar = 0u;
    for (int j = i; j < (B_ * H_) / 2; j += gridDim.x * 256)
        ((unsigned*)hA)[j] = 0u;
}

// ---------------- tiled transpose+convert: src fp32 [K][N] -> dst bf16 [n'][K] ----------------
__global__ void transpose_kernel(const float* __restrict__ src, ushort* __restrict__ dst,
                                 int K, int N, int perm) {
    __shared__ float tile[32][33];
    int kx = blockIdx.y * 32;
    int nx = blockIdx.x * 32;
    int c  = threadIdx.x & 31;
    int r0 = threadIdx.x >> 5;   // 0..7
    for (int rr = r0; rr < 32; rr += 8)
        tile[rr][c] = src[(size_t)(kx + rr) * N + nx + c];
    __syncthreads();
    for (int rr = r0; rr < 32; rr += 8) {
        int n  = nx + rr;
        int np = perm ? ((n & 1023) * 4 + (n >> 10)) : n;
        dst[(size_t)np * K + kx + c] = f2bf(tile[c][rr]);
    }
}

// ---------------- xW GEMM: C[m][n] = emb[tok[m]] @ W + b, stored as xWT[t][b][n'] bf16 ----------------
__global__ __launch_bounds__(256, 1) void gemm_xw_kernel(
    const int* __restrict__ tokens, const float* __restrict__ emb,
    const ushort* __restrict__ WT,  const float* __restrict__ bias,
    ushort* __restrict__ xWT) {
    const int tid = threadIdx.x;
    const int lane = tid & 63;
    const int w = tid >> 6;
    const int nb = blockIdx.x;   // 0..63
    const int mb = blockIdx.y;   // 0..255
    const int lr = lane & 15, lq = lane >> 4;

    const int mrow = mb * 64 + w * 16 + lr;          // A-frag row
    const int tok  = tokens[mrow];
    const float* arow = emb + (size_t)tok * E_;

    f32x4 acc[4] = {{0,0,0,0},{0,0,0,0},{0,0,0,0},{0,0,0,0}};
    #pragma unroll 4
    for (int ks = 0; ks < E_ / 32; ++ks) {
        const float* ap = arow + ks * 32 + lq * 8;
        float4 a0 = *reinterpret_cast<const float4*>(ap);
        float4 a1 = *reinterpret_cast<const float4*>(ap + 4);
        short8 af;
        af[0] = (short)f2bf(a0.x); af[1] = (short)f2bf(a0.y);
        af[2] = (short)f2bf(a0.z); af[3] = (short)f2bf(a0.w);
        af[4] = (short)f2bf(a1.x); af[5] = (short)f2bf(a1.y);
        af[6] = (short)f2bf(a1.z); af[7] = (short)f2bf(a1.w);
        #pragma unroll
        for (int s = 0; s < 4; ++s) {
            const ushort* brow = WT + (size_t)(nb * 64 + s * 16 + lr) * E_;
            short8 bf = *reinterpret_cast<const short8*>(brow + ks * 32 + lq * 8);
            acc[s] = __builtin_amdgcn_mfma_f32_16x16x32_bf16(af, bf, acc[s], 0, 0, 0);
        }
    }
    #pragma unroll
    for (int s = 0; s < 4; ++s) {
        int n = nb * 64 + s * 16 + lr;               // C col = lane&15
        float bv = bias[n];
        int np = (n & 1023) * 4 + (n >> 10);         // gate-interleaved col
        #pragma unroll
        for (int r = 0; r < 4; ++r) {
            int m  = mb * 64 + w * 16 + lq * 4 + r;  // C row = quad*4+reg
            int b  = m >> 9, t = m & 511;
            xWT[((size_t)t * B_ + b) * G4_ + np] = f2bf(acc[s][r] + bv);
        }
    }
}

// ---------------- persistent LSTM scan ----------------
// 128 blocks x 256 thr, all co-resident (64 KB LDS). Block owns 8 j-cols (32 n'-cols).
// U-slice stays in LDS; c,h in registers (replicated over the 4 gate-lanes);
// h broadcast via ping-pong global bf16 buffers + one device-scope barrier/step.
__global__ __launch_bounds__(256, 1) void scan_kernel(
    const ushort* __restrict__ UT,    // [4096][1024] bf16, row n' = j*4+gate
    const ushort* __restrict__ xWT,   // [512][32][4096] bf16 (n' order)
    const int* __restrict__ tokens,   // [32][512]
    ushort* hA, ushort* hB,           // [32][1024] bf16 ping-pong
    unsigned* bar,
    float* __restrict__ out) {        // [3][32][1024] fp32
    __shared__ short Us[NCOL_ * H_];  // chunk layout: entry e=(c*32+nl) holds 8 bf16, 64 KB

    const int tid  = threadIdx.x;
    const int blk  = blockIdx.x;
    const int lane = tid & 63;
    const int w    = tid >> 6;

    // one-time stage of U slice into chunked LDS layout
    for (int e = tid; e < NCOL_ * (H_ / 8); e += 256) {
        int c = e >> 5, nl = e & 31;
        short8 v = *reinterpret_cast<const short8*>(UT + (size_t)(blk * NCOL_ + nl) * H_ + c * 8);
        *reinterpret_cast<short8*>(&Us[e * 8]) = v;
    }
    __syncthreads();

    const int m0 = (w & 1) * 16;          // batch-row tile
    const int n0 = (w >> 1) * 16;         // block-local col tile
    const int lr = lane & 15;
    const int lq = lane >> 4;
    const int g  = lane & 3;              // gate id (n' = j*4+gate)
    const int nl = n0 + lr;
    const int ng = blk * NCOL_ + nl;      // global n'
    const int jg = ng >> 2;               // global j

    float creg[4] = {0, 0, 0, 0};
    float hreg[4] = {0, 0, 0, 0};

    const ushort* hcur = hA;              // zero-initialized
    ushort*       hnxt = hB;

    for (int t = 0; t < S_; ++t) {
        // z-tile = h @ Uslice  (16x16x32 MFMA, K=1024)
        f32x4 acc = {0, 0, 0, 0};
        const ushort* hrow = hcur + (size_t)(m0 + lr) * H_;
        #pragma unroll
        for (int ks = 0; ks < H_ / 32; ++ks) {
            short8 af = *reinterpret_cast<const short8*>(hrow + ks * 32 + lq * 8);
            short8 bf = *reinterpret_cast<const short8*>(&Us[((ks * 4 + lq) * 32 + nl) * 8]);
            acc = __builtin_amdgcn_mfma_f32_16x16x32_bf16(af, bf, acc, 0, 0, 0);
        }
        const ushort* xwt = xWT + (size_t)t * B_ * G4_;
        #pragma unroll
        for (int r = 0; r < 4; ++r) {
            int row = m0 + lq * 4 + r;    // batch index
            float z  = acc[r] + bf2f(xwt[(size_t)row * G4_ + ng]);
            float tg = tanh_fast(z);
            float x1 = __shfl_xor(tg, 1, 64);
            float x2 = __shfl_xor(tg, 2, 64);
            float x3 = __shfl_xor(tg, 3, 64);
            float tI = sel4(g,     tg, x1, x2, x3);
            float tF = sel4(g ^ 1, tg, x1, x2, x3);
            float tG = sel4(g ^ 2, tg, x1, x2, x3);
            float tO = sel4(g ^ 3, tg, x1, x2, x3);
            float cn = tF * creg[r] + tI * tG;
            float hn = tO * tanh_fast(cn);
            int tok = tokens[row * S_ + t];
            if (tok != 0) { creg[r] = cn; hreg[r] = hn; }
        }
        if (t < S_ - 1) {
            if (g == 0) {
                #pragma unroll
                for (int r = 0; r < 4; ++r) {
                    int row = m0 + lq * 4 + r;
                    hnxt[row * H_ + jg] = f2bf(hreg[r]);
                }
            }
            __syncthreads();              // drains vmcnt: block's stores are in L2
            if (tid == 0) {
                __threadfence();          // release: wbl2 -> visible past XCD
                __hip_atomic_fetch_add(bar, 1u, __ATOMIC_RELAXED, __HIP_MEMORY_SCOPE_AGENT);
                unsigned target = (unsigned)(t + 1) * NB_;
                while (__hip_atomic_load(bar, __ATOMIC_RELAXED, __HIP_MEMORY_SCOPE_AGENT) < target)
                    __builtin_amdgcn_s_sleep(1);
                __threadfence();          // acquire: inv L1/L2
            }
            __syncthreads();
            ushort* tmp = (ushort*)hcur; hcur = hnxt; hnxt = tmp;
        } else {
            if (g == 0) {
                #pragma unroll
                for (int r = 0; r < 4; ++r) {
                    int row = m0 + lq * 4 + r;
                    out[row * H_ + jg]               = hreg[r];
                    out[B_ * H_ + row * H_ + jg]     = hreg[r];
                    out[2 * B_ * H_ + row * H_ + jg] = creg[r];
                }
            }
        }
    }
}

extern "C" void kernel_launch(void* const* d_in, const int* in_sizes, int n_in,
                              void* d_out, int out_size, void* d_ws, size_t ws_size,
                              hipStream_t stream) {
    (void)in_sizes; (void)n_in; (void)out_size; (void)ws_size;
    const int*   tokens = (const int*)  d_in[0];
    const float* emb    = (const float*)d_in[1];
    const float* W      = (const float*)d_in[2];
    const float* U      = (const float*)d_in[3];
    const float* bias   = (const float*)d_in[4];

    char* ws = (char*)d_ws;
    ushort*   UT  = (ushort*)ws;                                  // 8 MB
    ushort*   WT  = (ushort*)(ws + (8u  << 20));                  // 4 MB
    ushort*   xWT = (ushort*)(ws + (12u << 20));                  // 128 MB
    ushort*   hA  = (ushort*)(ws + (12u << 20) + (128u << 20));   // 64 KB
    ushort*   hB  = hA + B_ * H_;                                 // 64 KB
    unsigned* bar = (unsigned*)(hA + 2 * B_ * H_);

    init_kernel<<<16, 256, 0, stream>>>(hA, bar);
    transpose_kernel<<<dim3(G4_ / 32, H_ / 32), 256, 0, stream>>>(U, UT, H_, G4_, 1);
    transpose_kernel<<<dim3(G4_ / 32, E_ / 32), 256, 0, stream>>>(W, WT, E_, G4_, 0);
    gemm_xw_kernel<<<dim3(G4_ / 64, (B_ * S_) / 64), 256, 0, stream>>>(tokens, emb, WT, bias, xWT);
    scan_kernel<<<NB_, 256, 0, stream>>>(UT, xWT, tokens, hA, hB, bar, (float*)d_out);
}

// Round 3
// 3490.638 us; speedup vs baseline: 2.2429x; 2.2429x over previous
//
#include <hip/hip_runtime.h>
#include <hip/hip_bf16.h>

// Problem constants
#define B_    32
#define S_    512
#define E_    512
#define H_    1024          // U_DIM
#define G4_   4096          // 4*U_DIM
#define NB_   128           // persistent scan blocks
#define NCOL_ 32            // n'-cols per scan block (8 j * 4 gates)
#define HROW_ 1032          // padded LDS row stride in shorts (+16B: 2-way banks = free)

typedef __attribute__((ext_vector_type(8))) short short8;
typedef __attribute__((ext_vector_type(4))) float f32x4;
typedef unsigned long long u64;

__device__ __forceinline__ float bf2f(ushort u) {
    union { unsigned u32; float f; } cv; cv.u32 = ((unsigned)u) << 16; return cv.f;
}
__device__ __forceinline__ ushort f2bf(float f) {
    union { float f; unsigned u; } cv; cv.f = f;
    unsigned u = cv.u;
    u += 0x7FFFu + ((u >> 16) & 1u);   // RNE
    return (ushort)(u >> 16);
}
__device__ __forceinline__ float tanh_fast(float x) {
    float e = __builtin_amdgcn_exp2f(x * 2.885390081777927f);
    return 1.0f - 2.0f * __builtin_amdgcn_rcpf(e + 1.0f);
}
__device__ __forceinline__ float sel4(int s, float a0, float a1, float a2, float a3) {
    return (s & 2) ? ((s & 1) ? a3 : a2) : ((s & 1) ? a1 : a0);
}

// ---------------- init: zero h0, flags, release ----------------
__global__ void init_kernel(u64* hA, unsigned* flags, unsigned* rel) {
    int i = blockIdx.x * 256 + threadIdx.x;
    for (int j = i; j < (B_ * H_) / 4; j += gridDim.x * 256) hA[j] = 0ull;
    if (i < NB_) flags[i] = 0u;
    if (i == 0) *rel = 0u;
}

// ---------------- tiled transpose+convert: src fp32 [K][N] -> dst bf16 [n'][K] ----------------
__global__ void transpose_kernel(const float* __restrict__ src, ushort* __restrict__ dst,
                                 int K, int N, int perm) {
    __shared__ float tile[32][33];
    int kx = blockIdx.y * 32;
    int nx = blockIdx.x * 32;
    int c  = threadIdx.x & 31;
    int r0 = threadIdx.x >> 5;
    for (int rr = r0; rr < 32; rr += 8)
        tile[rr][c] = src[(size_t)(kx + rr) * N + nx + c];
    __syncthreads();
    for (int rr = r0; rr < 32; rr += 8) {
        int n  = nx + rr;
        int np = perm ? ((n & 1023) * 4 + (n >> 10)) : n;
        dst[(size_t)np * K + kx + c] = f2bf(tile[c][rr]);
    }
}

// ---------------- xW GEMM: emb[tok] @ W + b  -> xWT[t][n'][b] bf16 ----------------
__global__ __launch_bounds__(256, 1) void gemm_xw_kernel(
    const int* __restrict__ tokens, const float* __restrict__ emb,
    const ushort* __restrict__ WT,  const float* __restrict__ bias,
    ushort* __restrict__ xWT) {
    const int tid = threadIdx.x;
    const int lane = tid & 63;
    const int w = tid >> 6;
    const int nb = blockIdx.x;   // 0..63
    const int mb = blockIdx.y;   // 0..255
    const int lr = lane & 15, lq = lane >> 4;

    const int mrow = mb * 64 + w * 16 + lr;
    const int tok  = tokens[mrow];
    const float* arow = emb + (size_t)tok * E_;

    f32x4 acc[4] = {{0,0,0,0},{0,0,0,0},{0,0,0,0},{0,0,0,0}};
    #pragma unroll 4
    for (int ks = 0; ks < E_ / 32; ++ks) {
        const float* ap = arow + ks * 32 + lq * 8;
        float4 a0 = *reinterpret_cast<const float4*>(ap);
        float4 a1 = *reinterpret_cast<const float4*>(ap + 4);
        short8 af;
        af[0] = (short)f2bf(a0.x); af[1] = (short)f2bf(a0.y);
        af[2] = (short)f2bf(a0.z); af[3] = (short)f2bf(a0.w);
        af[4] = (short)f2bf(a1.x); af[5] = (short)f2bf(a1.y);
        af[6] = (short)f2bf(a1.z); af[7] = (short)f2bf(a1.w);
        #pragma unroll
        for (int s = 0; s < 4; ++s) {
            const ushort* brow = WT + (size_t)(nb * 64 + s * 16 + lr) * E_;
            short8 bf = *reinterpret_cast<const short8*>(brow + ks * 32 + lq * 8);
            acc[s] = __builtin_amdgcn_mfma_f32_16x16x32_bf16(af, bf, acc[s], 0, 0, 0);
        }
    }
    #pragma unroll
    for (int s = 0; s < 4; ++s) {
        int n = nb * 64 + s * 16 + lr;
        float bv = bias[n];
        int np = (n & 1023) * 4 + (n >> 10);         // gate-interleaved col
        #pragma unroll
        for (int r = 0; r < 4; ++r) {
            int m  = mb * 64 + w * 16 + lq * 4 + r;
            int b  = m >> 9, t = m & 511;
            xWT[((size_t)t * G4_ + np) * B_ + b] = f2bf(acc[s][r] + bv);
        }
    }
}

// ---------------- persistent LSTM scan (fence-free lockstep) ----------------
// 128 blocks x 256 thr. Block owns 32 n'-cols of U in LDS. h exchanged via LLC
// (agent-scope relaxed atomics = sc1, bypass L2 -> no invalidates needed).
// Barrier: distributed arrival flags + gather wave in block 0 + release word.
__global__ __launch_bounds__(256, 1) void scan_kernel(
    const ushort* __restrict__ UT,    // [4096][1024] bf16, row n' = j*4+gate
    const ushort* __restrict__ xWT,   // [512][4096][32] bf16
    const int* __restrict__ tokens,   // [32][512]
    u64* hA, u64* hB,                 // [32][1024] bf16 (as u64 chunks), ping-pong
    unsigned* flags, unsigned* rel,
    float* __restrict__ out) {        // [3][32][1024] fp32
    __shared__ short  Us[NCOL_ * H_];      // 64 KB: entry e=(c*32+nl) holds 8 bf16
    __shared__ ushort Hs[B_ * HROW_];      // 66 KB: padded [row][k]

    const int tid  = threadIdx.x;
    const int blk  = blockIdx.x;
    const int lane = tid & 63;
    const int w    = tid >> 6;

    // one-time stage of U slice into chunked LDS layout
    for (int e = tid; e < NCOL_ * (H_ / 8); e += 256) {
        int c = e >> 5, nl0 = e & 31;
        short8 v = *reinterpret_cast<const short8*>(UT + (size_t)(blk * NCOL_ + nl0) * H_ + c * 8);
        *reinterpret_cast<short8*>(&Us[e * 8]) = v;
    }

    const int m0 = (w & 1) * 16;          // batch-row tile
    const int n0 = (w >> 1) * 16;         // block-local col tile
    const int lr = lane & 15;
    const int lq = lane >> 4;
    const int g  = lane & 3;              // gate id (n' = j*4+gate)
    const int nl = n0 + lr;
    const int ng = blk * NCOL_ + nl;      // global n'
    const int jg0 = blk * 8 + (w >> 1) * 4;  // first j-col this wave packs

    float creg[4] = {0, 0, 0, 0};
    float hreg[4] = {0, 0, 0, 0};

    const u64* hcur = hA;                 // zero-initialized
    u64*       hnxt = hB;

    for (int t = 0; t < S_; ++t) {
        // ---- stage h (LLC, sc1) into padded LDS [row][k]; 32 loads in flight ----
        {
            u64 tmp[32];
            #pragma unroll
            for (int i = 0; i < 32; ++i)
                tmp[i] = __hip_atomic_load(hcur + tid + i * 256,
                                           __ATOMIC_RELAXED, __HIP_MEMORY_SCOPE_AGENT);
            #pragma unroll
            for (int i = 0; i < 32; ++i) {
                int e = tid + i * 256;
                int row = e >> 8, kc = e & 255;           // 256 u64 per row
                *reinterpret_cast<u64*>(&Hs[row * HROW_ + kc * 4]) = tmp[i];
            }
        }
        // prefetch xw (one 8B load/lane) and token masks while staging drains
        const ushort* xwt = xWT + (size_t)t * (G4_ * B_);
        u64 xwv = *reinterpret_cast<const u64*>(xwt + (size_t)ng * B_ + m0 + lq * 4);
        int tok[4];
        #pragma unroll
        for (int r = 0; r < 4; ++r) tok[r] = tokens[(m0 + lq * 4 + r) * S_ + t];
        __syncthreads();

        // ---- z-tile = h @ Uslice (two independent MFMA chains) ----
        f32x4 acc0 = {0, 0, 0, 0}, acc1 = {0, 0, 0, 0};
        #pragma unroll
        for (int ks = 0; ks < 32; ks += 2) {
            short8 a0 = *reinterpret_cast<const short8*>(&Hs[(m0 + lr) * HROW_ + ks * 32 + lq * 8]);
            short8 b0 = *reinterpret_cast<const short8*>(&Us[((ks * 4 + lq) * 32 + nl) * 8]);
            acc0 = __builtin_amdgcn_mfma_f32_16x16x32_bf16(a0, b0, acc0, 0, 0, 0);
            short8 a1 = *reinterpret_cast<const short8*>(&Hs[(m0 + lr) * HROW_ + (ks + 1) * 32 + lq * 8]);
            short8 b1 = *reinterpret_cast<const short8*>(&Us[(((ks + 1) * 4 + lq) * 32 + nl) * 8]);
            acc1 = __builtin_amdgcn_mfma_f32_16x16x32_bf16(a1, b1, acc1, 0, 0, 0);
        }

        // ---- gates ----
        #pragma unroll
        for (int r = 0; r < 4; ++r) {
            float z  = acc0[r] + acc1[r] + bf2f((ushort)(xwv >> (16 * r)));
            float tg = tanh_fast(z);
            float x1 = __shfl_xor(tg, 1, 64);
            float x2 = __shfl_xor(tg, 2, 64);
            float x3 = __shfl_xor(tg, 3, 64);
            float tI = sel4(g,     tg, x1, x2, x3);
            float tF = sel4(g ^ 1, tg, x1, x2, x3);
            float tG = sel4(g ^ 2, tg, x1, x2, x3);
            float tO = sel4(g ^ 3, tg, x1, x2, x3);
            float cn = tF * creg[r] + tI * tG;
            float hn = tO * tanh_fast(cn);
            if (tok[r] != 0) { creg[r] = cn; hreg[r] = hn; }
        }

        if (t < S_ - 1) {
            // ---- pack h across lanes lr=0,4,8,12 -> 8B stores, [row][j] layout ----
            unsigned hb[4];
            #pragma unroll
            for (int r = 0; r < 4; ++r) hb[r] = (unsigned)f2bf(hreg[r]);
            u64 pv[4];
            #pragma unroll
            for (int r = 0; r < 4; ++r) {
                unsigned x4  = (unsigned)__shfl_xor((int)hb[r], 4, 64);
                unsigned x8  = (unsigned)__shfl_xor((int)hb[r], 8, 64);
                unsigned x12 = (unsigned)__shfl_xor((int)hb[r], 12, 64);
                u64 lo = (u64)(hb[r] | (x4 << 16));
                u64 hi = (u64)(x8 | (x12 << 16));
                pv[r] = lo | (hi << 32);
            }
            if (lr == 0) {
                #pragma unroll
                for (int r = 0; r < 4; ++r) {
                    int row = m0 + lq * 4 + r;
                    __hip_atomic_store(hnxt + ((size_t)row * H_ + jg0) / 4, pv[r],
                                       __ATOMIC_RELAXED, __HIP_MEMORY_SCOPE_AGENT);
                }
            }
            __syncthreads();              // all waves' h stores drained (vmcnt 0)

            // ---- distributed barrier ----
            unsigned tv = (unsigned)(t + 1);
            if (tid == 0)
                __hip_atomic_store(&flags[blk], tv, __ATOMIC_RELAXED, __HIP_MEMORY_SCOPE_AGENT);
            if (blk == 0) {
                if (tid < 64) {
                    for (;;) {
                        unsigned a = __hip_atomic_load(&flags[tid],      __ATOMIC_RELAXED, __HIP_MEMORY_SCOPE_AGENT);
                        unsigned b = __hip_atomic_load(&flags[tid + 64], __ATOMIC_RELAXED, __HIP_MEMORY_SCOPE_AGENT);
                        if (__all(a >= tv && b >= tv)) break;
                        __builtin_amdgcn_s_sleep(2);
                    }
                }
                if (tid == 0)
                    __hip_atomic_store(rel, tv, __ATOMIC_RELAXED, __HIP_MEMORY_SCOPE_AGENT);
            } else if (tid == 0) {
                while (__hip_atomic_load(rel, __ATOMIC_RELAXED, __HIP_MEMORY_SCOPE_AGENT) < tv)
                    __builtin_amdgcn_s_sleep(2);
            }
            __syncthreads();              // release observed -> safe to read hnxt
            u64* tswap = (u64*)hcur; hcur = hnxt; hnxt = tswap;
        } else {
            // ---- final step: write (h, h, c) fp32 ----
            if (g == 0) {
                int jgl = jg0 + (lr >> 2);
                #pragma unroll
                for (int r = 0; r < 4; ++r) {
                    int row = m0 + lq * 4 + r;
                    out[row * H_ + jgl]               = hreg[r];
                    out[B_ * H_ + row * H_ + jgl]     = hreg[r];
                    out[2 * B_ * H_ + row * H_ + jgl] = creg[r];
                }
            }
        }
    }
}

extern "C" void kernel_launch(void* const* d_in, const int* in_sizes, int n_in,
                              void* d_out, int out_size, void* d_ws, size_t ws_size,
                              hipStream_t stream) {
    (void)in_sizes; (void)n_in; (void)out_size; (void)ws_size;
    const int*   tokens = (const int*)  d_in[0];
    const float* emb    = (const float*)d_in[1];
    const float* W      = (const float*)d_in[2];
    const float* U      = (const float*)d_in[3];
    const float* bias   = (const float*)d_in[4];

    char* ws = (char*)d_ws;
    ushort*   UT  = (ushort*)ws;                                  // 8 MB
    ushort*   WT  = (ushort*)(ws + (8u  << 20));                  // 4 MB
    ushort*   xWT = (ushort*)(ws + (12u << 20));                  // 128 MB
    u64*      hA  = (u64*)   (ws + (12u << 20) + (128u << 20));   // 64 KB
    u64*      hB  = hA + (B_ * H_) / 4;                           // 64 KB
    unsigned* flags = (unsigned*)(hB + (B_ * H_) / 4);            // 512 B
    unsigned* rel   = flags + NB_;

    init_kernel<<<16, 256, 0, stream>>>(hA, flags, rel);
    transpose_kernel<<<dim3(G4_ / 32, H_ / 32), 256, 0, stream>>>(U, UT, H_, G4_, 1);
    transpose_kernel<<<dim3(G4_ / 32, E_ / 32), 256, 0, stream>>>(W, WT, E_, G4_, 0);
    gemm_xw_kernel<<<dim3(G4_ / 64, (B_ * S_) / 64), 256, 0, stream>>>(tokens, emb, WT, bias, xWT);
    scan_kernel<<<NB_, 256, 0, stream>>>(UT, xWT, tokens, hA, hB, flags, rel, (float*)d_out);
}